// Round 12
// baseline (437.000 us; speedup 1.0000x reference)
//
#include <hip/hip_runtime.h>
#include <hip/hip_bf16.h>

#define NV 4096
#define NE 8192
#define AD 64      // ATOM_DIM
#define BD 32      // BOND_DIM_P1
#define HD 128     // H
#define NL 4       // N_LAYER
#define DEGCAP 32  // adjacency bucket capacity (lambda=2 Poisson, max deg << 32)

// Everything is fp32 (proven r6-r11).

__device__ __forceinline__ float leaky(float x) { return x > 0.f ? x : 0.01f * x; }
__device__ __forceinline__ int clampv(int x) { return min(max(x, 0), NV - 1); }

// ---- fp32 weight scratch layout (float offsets), proven r3/r6-r11 ----
#define W_VW1T 0           // [64][128]   Wt[k][j] = W[j][k]
#define W_VW2T 8192        // [128][128]
#define W_EW1T 24576       // [32][128]
#define W_EW2T 28672       // [128][128]
#define W_MWT  45056       // [4][128][128]
#define W_VB1  110592
#define W_VB2  110720
#define W_EB1  110848
#define W_EB2  110976
#define W_MB   111104      // [4][128]
#define W_TOTAL 111616     // = 436 * 256 exactly

// ---- out layout (float offsets): [hv 524288][per-edge 384: src|dst|he] ----
#define OUT_HE 524288
#define ESTR   384

// ---- ws layout (byte offsets), r11-proven ----
#define WS_SRC 0            // NE ints
#define WS_DST 32768        // NE ints
#define WS_DEG 65536        // NV ints
#define WS_ADJ 81920        // NV*DEGCAP ints (512 KB)
#define WS_WB  606208       // W_TOTAL floats
#define WS_HVA 1052672      // NV*HD floats (2 MB)
#define WS_HVB 3149824      // NV*HD floats (2 MB)

// ---------------------------------------------------------------------------
// dispatch 1 (tiny): weight transpose + bias copy (r3-proven map) + deg = 0
// blocks [0,436): weights; [436,452): deg
// ---------------------------------------------------------------------------
__global__ void prep_k(const float* __restrict__ vW1, const float* __restrict__ vW2,
                       const float* __restrict__ eW1, const float* __restrict__ eW2,
                       const float* __restrict__ mW,
                       const float* __restrict__ vb1, const float* __restrict__ vb2,
                       const float* __restrict__ eb1, const float* __restrict__ eb2,
                       const float* __restrict__ mb, float* __restrict__ wb,
                       int* __restrict__ deg) {
    int blk = blockIdx.x, t = threadIdx.x;
    if (blk < 436) {
        int i = blk * 256 + t;
        if (i >= W_TOTAL) return;
        float v;
        if (i < W_VW2T)      { int q = i;          int k = q / 128, j = q % 128; v = vW1[(long)j * AD + k]; }
        else if (i < W_EW1T) { int q = i - W_VW2T; int k = q / 128, j = q % 128; v = vW2[(long)j * HD + k]; }
        else if (i < W_EW2T) { int q = i - W_EW1T; int k = q / 128, j = q % 128; v = eW1[(long)j * BD + k]; }
        else if (i < W_MWT)  { int q = i - W_EW2T; int k = q / 128, j = q % 128; v = eW2[(long)j * HD + k]; }
        else if (i < W_VB1)  { int q = i - W_MWT;  int l = q / 16384, r = q % 16384;
                               int k = r / 128, j = r % 128;
                               v = mW[(long)l * 16384 + (long)j * HD + k]; }
        else if (i < W_VB2)  v = vb1[i - W_VB1];
        else if (i < W_EB1)  v = vb2[i - W_VB2];
        else if (i < W_EB2)  v = eb1[i - W_EB1];
        else if (i < W_MB)   v = eb2[i - W_EB2];
        else                 v = mb[i - W_MB];
        wb[i] = v;
    } else {
        int i = (blk - 436) * 256 + t;
        if (i < NV) deg[i] = 0;
    }
}

// micro-GEMM (proven r3/r6-r11): thread computes one row x cols [4jg,4jg+4)
template<int K>
__device__ __forceinline__ float4 gemm_row(const float* __restrict__ xrow,
                                           const float* __restrict__ Wt, int jg) {
    float4 c = make_float4(0.f, 0.f, 0.f, 0.f);
    const float4* W4 = (const float4*)Wt;
#pragma unroll 8
    for (int k = 0; k < K; k += 4) {
        float4 xv = *(const float4*)(xrow + k);
        float4 w0 = W4[(k + 0) * 32 + jg];
        float4 w1 = W4[(k + 1) * 32 + jg];
        float4 w2 = W4[(k + 2) * 32 + jg];
        float4 w3 = W4[(k + 3) * 32 + jg];
        c.x = fmaf(xv.x, w0.x, fmaf(xv.y, w1.x, fmaf(xv.z, w2.x, fmaf(xv.w, w3.x, c.x))));
        c.y = fmaf(xv.x, w0.y, fmaf(xv.y, w1.y, fmaf(xv.z, w2.y, fmaf(xv.w, w3.y, c.y))));
        c.z = fmaf(xv.x, w0.z, fmaf(xv.y, w1.z, fmaf(xv.z, w2.z, fmaf(xv.w, w3.z, c.z))));
        c.w = fmaf(xv.x, w0.w, fmaf(xv.y, w1.w, fmaf(xv.z, w2.w, fmaf(xv.w, w3.w, c.w))));
    }
    return c;
}

// ---------------------------------------------------------------------------
// dispatch 2 (the memory wall + hidden compute), 256 thr/block:
// blocks [0,2048):    extract (r8-proven body). vew1 half also fills deg/adj
//                     directly in the rare path (deg zeroed by prep_k).
// blocks [2048,2560): node input MLP, 8 rows/block -> hvA
// blocks [2560,3584): edge input MLP, 8 rows/block -> he out slot
// Extract blocks idle on memory (VALUBusy 2%); GEMM blocks co-schedule on the
// same CUs and hide inside the ~100 us wall (m114 overlap).
// ---------------------------------------------------------------------------
__global__ __launch_bounds__(256, 3)
void fused_k(const uint4* __restrict__ vew1, const uint4* __restrict__ vew2,
             int* __restrict__ srcv, int* __restrict__ dstv,
             int* __restrict__ deg, int* __restrict__ adj,
             const float* __restrict__ atom, const float* __restrict__ bond,
             const float* __restrict__ wb,
             float* __restrict__ hv, float* __restrict__ outf) {
    __shared__ __align__(16) float xs[8 * AD];   // 2 KB (node path max)
    __shared__ __align__(16) float t1[8 * HD];   // 4 KB
    int blk = blockIdx.x, t = threadIdx.x;
    if (blk < 2048) {
        bool isv1 = (blk < 1024);
        const uint4* m = isv1 ? vew1 : vew2;
        int* out = isv1 ? srcv : dstv;
        int r0 = (blk & 1023) * 4;
        const uint4* p = m + (long)r0 * 2048;
#pragma unroll
        for (int b = 0; b < 2; b++) {
            uint4 u[16];
            unsigned o[16];
            int base = b * 4096 + t;
#pragma unroll
            for (int k = 0; k < 16; k++) u[k] = p[base + k * 256];
#pragma unroll
            for (int k = 0; k < 16; k++) o[k] = u[k].x | u[k].y | u[k].z | u[k].w;
            unsigned any = 0;
#pragma unroll
            for (int k = 0; k < 16; k++) any |= o[k];
            if (any == 0u) continue;
#pragma unroll
            for (int k = 0; k < 16; k++) {
                if (o[k] == 0u) continue;
                int i = base + k * 256;
                int row = r0 + (i >> 11);
                int col = (i << 2) & (NE - 1);
#pragma unroll
                for (int q = 0; q < 4; q++) {
                    unsigned val = (q == 0) ? u[k].x : (q == 1) ? u[k].y
                                 : (q == 2) ? u[k].z : u[k].w;
                    if (val) {
                        int e = col + q;
                        out[e] = row;
                        if (isv1) {                    // src-adjacency fill
                            int pp = atomicAdd(&deg[row], 1);
                            if (pp < DEGCAP) adj[row * DEGCAP + pp] = e;
                        }
                    }
                }
            }
        }
    } else if (blk < 2560) {
        // node input MLP: hv = tanh(leaky(atom@vW1.T+b1)@vW2.T+b2), 8 rows
        int r0 = (blk - 2048) * 8;
        int jg = t & 31, rg = t >> 5, j0 = jg * 4;
        for (int i = t; i < 8 * AD; i += 256) xs[i] = atom[(long)r0 * AD + i];
        __syncthreads();
        float4 c1 = gemm_row<AD>(xs + rg * AD, wb + W_VW1T, jg);
        float4 b1 = *(const float4*)(wb + W_VB1 + j0);
        c1.x = leaky(c1.x + b1.x); c1.y = leaky(c1.y + b1.y);
        c1.z = leaky(c1.z + b1.z); c1.w = leaky(c1.w + b1.w);
        *(float4*)(t1 + rg * HD + j0) = c1;
        __syncthreads();
        float4 c2 = gemm_row<HD>(t1 + rg * HD, wb + W_VW2T, jg);
        float4 b2 = *(const float4*)(wb + W_VB2 + j0);
        c2.x = tanhf(c2.x + b2.x); c2.y = tanhf(c2.y + b2.y);
        c2.z = tanhf(c2.z + b2.z); c2.w = tanhf(c2.w + b2.w);
        *(float4*)(hv + (long)(r0 + rg) * HD + j0) = c2;
    } else {
        // edge input MLP -> he straight into final out slot, 8 rows
        int r0 = (blk - 2560) * 8;
        int jg = t & 31, rg = t >> 5, j0 = jg * 4;
        if (t < 8 * BD) xs[t] = bond[(long)r0 * BD + t];
        __syncthreads();
        float4 c1 = gemm_row<BD>(xs + rg * BD, wb + W_EW1T, jg);
        float4 b1 = *(const float4*)(wb + W_EB1 + j0);
        c1.x = leaky(c1.x + b1.x); c1.y = leaky(c1.y + b1.y);
        c1.z = leaky(c1.z + b1.z); c1.w = leaky(c1.w + b1.w);
        *(float4*)(t1 + rg * HD + j0) = c1;
        __syncthreads();
        float4 c2 = gemm_row<HD>(t1 + rg * HD, wb + W_EW2T, jg);
        float4 b2 = *(const float4*)(wb + W_EB2 + j0);
        c2.x = tanhf(c2.x + b2.x); c2.y = tanhf(c2.y + b2.y);
        c2.z = tanhf(c2.z + b2.z); c2.w = tanhf(c2.w + b2.w);
        *(float4*)(outf + (long)OUT_HE + (long)(r0 + rg) * ESTR + 2 * HD + j0) = c2;
    }
}

// ---------------------------------------------------------------------------
// fused layer (r11-proven verbatim): gather + MLP, no atomics
// ---------------------------------------------------------------------------
__global__ void layer_k(const float* __restrict__ hvin, const float* __restrict__ wb,
                        const int* __restrict__ deg, const int* __restrict__ adj,
                        const int* __restrict__ dstv, const float* __restrict__ outf,
                        float* __restrict__ hvout, int l, float* hv_out) {
    __shared__ __align__(16) float xs[4 * HD];
    int t = threadIdx.x, jg = t & 31, rg = t >> 5, j0 = jg * 4;
    int r = blockIdx.x * 4 + rg;
    float4 x = *(const float4*)(hvin + (long)r * HD + j0);
    int dn = min(deg[r], DEGCAP);
    const int* al = adj + r * DEGCAP;
    for (int i = 0; i < dn; i++) {
        int e = al[i]; e = max(0, min(e, NE - 1));
        int d = clampv(dstv[e]);
        float4 he = *(const float4*)(outf + (long)OUT_HE + (long)e * ESTR + 2 * HD + j0);
        float4 hd = *(const float4*)(hvin + (long)d * HD + j0);
        float s0 = he.x + hd.x, s1 = he.y + hd.y;
        float s2 = he.z + hd.z, s3 = he.w + hd.w;
        x.x += s0 > 0.f ? s0 : 0.f; x.y += s1 > 0.f ? s1 : 0.f;
        x.z += s2 > 0.f ? s2 : 0.f; x.w += s3 > 0.f ? s3 : 0.f;
    }
    *(float4*)(xs + rg * HD + j0) = x;
    __syncthreads();
    float4 c = gemm_row<HD>(xs + rg * HD, wb + W_MWT + l * 16384, jg);
    float4 b = *(const float4*)(wb + W_MB + l * HD + j0);
    c.x = leaky(c.x + b.x); c.y = leaky(c.y + b.y);
    c.z = leaky(c.z + b.z); c.w = leaky(c.w + b.w);
    long o = (long)r * HD + j0;
    *(float4*)(hvout + o) = c;
    if (hv_out) *(float4*)(hv_out + o) = c;
}

// gather sections (r11-proven verbatim)
__global__ void out_he_k(const float* __restrict__ hv,
                         const int* __restrict__ src, const int* __restrict__ dst,
                         float* __restrict__ outf) {
    int e = blockIdx.x, t = threadIdx.x, j0 = t * 2;
    int s = clampv(src[e]), d = clampv(dst[e]);
    float2 a = *(const float2*)(hv + (long)s * HD + j0);
    float2 b = *(const float2*)(hv + (long)d * HD + j0);
    float* base = outf + (long)OUT_HE + (long)e * ESTR;
    *(float2*)(base + j0) = a;
    *(float2*)(base + HD + j0) = b;
}

extern "C" void kernel_launch(void* const* d_in, const int* in_sizes, int n_in,
                              void* d_out, int out_size, void* d_ws, size_t ws_size,
                              hipStream_t stream) {
    char* ws = (char*)d_ws;
    int*   srcv = (int*)(ws + WS_SRC);
    int*   dstv = (int*)(ws + WS_DST);
    int*   deg  = (int*)(ws + WS_DEG);
    int*   adj  = (int*)(ws + WS_ADJ);
    float* wb   = (float*)(ws + WS_WB);
    float* hvA  = (float*)(ws + WS_HVA);
    float* hvB  = (float*)(ws + WS_HVB);
    float* outf = (float*)d_out;

    prep_k<<<452, 256, 0, stream>>>(
        (const float*)d_in[4], (const float*)d_in[6], (const float*)d_in[8],
        (const float*)d_in[10], (const float*)d_in[12],
        (const float*)d_in[5], (const float*)d_in[7], (const float*)d_in[9],
        (const float*)d_in[11], (const float*)d_in[13], wb, deg);

    fused_k<<<3584, 256, 0, stream>>>(
        (const uint4*)d_in[2], (const uint4*)d_in[3], srcv, dstv, deg, adj,
        (const float*)d_in[0], (const float*)d_in[1], wb, hvA, outf);

    // ping-pong: A->B->A->B->A (final hv in A)
    layer_k<<<NV / 4, 128, 0, stream>>>(hvA, wb, deg, adj, dstv, outf, hvB, 0, nullptr);
    layer_k<<<NV / 4, 128, 0, stream>>>(hvB, wb, deg, adj, dstv, outf, hvA, 1, nullptr);
    layer_k<<<NV / 4, 128, 0, stream>>>(hvA, wb, deg, adj, dstv, outf, hvB, 2, nullptr);
    layer_k<<<NV / 4, 128, 0, stream>>>(hvB, wb, deg, adj, dstv, outf, hvA, 3, outf);

    out_he_k<<<NE, 64, 0, stream>>>(hvA, srcv, dstv, outf);
}

// Round 13
// 410.639 us; speedup vs baseline: 1.0642x; 1.0642x over previous
//
#include <hip/hip_runtime.h>
#include <hip/hip_bf16.h>

#define NV 4096
#define NE 8192
#define AD 64      // ATOM_DIM
#define BD 32      // BOND_DIM_P1
#define HD 128     // H
#define NL 4       // N_LAYER
#define DEGCAP 32  // adjacency bucket capacity (lambda=2 Poisson, max deg << 32)

// Everything is fp32 (proven r6-r12).

__device__ __forceinline__ float leaky(float x) { return x > 0.f ? x : 0.01f * x; }
__device__ __forceinline__ int clampv(int x) { return min(max(x, 0), NV - 1); }

// ---- fp32 weight scratch layout (float offsets), proven r3/r6-r12 ----
#define W_VW1T 0           // [64][128]   Wt[k][j] = W[j][k]
#define W_VW2T 8192        // [128][128]
#define W_EW1T 24576       // [32][128]
#define W_EW2T 28672       // [128][128]
#define W_MWT  45056       // [4][128][128]
#define W_VB1  110592
#define W_VB2  110720
#define W_EB1  110848
#define W_EB2  110976
#define W_MB   111104      // [4][128]
#define W_TOTAL 111616     // = 436 * 256 exactly

// ---- out layout (float offsets): [hv 524288][per-edge 384: src|dst|he] ----
#define OUT_HE 524288
#define ESTR   384

// ---- ws layout (byte offsets), r11/r12-proven ----
#define WS_SRC 0            // NE ints
#define WS_DST 32768        // NE ints
#define WS_DEG 65536        // NV ints
#define WS_ADJ 81920        // NV*DEGCAP ints (512 KB)
#define WS_WB  606208       // W_TOTAL floats
#define WS_HVA 1052672      // NV*HD floats (2 MB)
#define WS_HVB 3149824      // NV*HD floats (2 MB)

// ---------------------------------------------------------------------------
// dispatch 1 (tiny, r12-proven): weight transpose + bias copy + deg = 0
// ---------------------------------------------------------------------------
__global__ void prep_k(const float* __restrict__ vW1, const float* __restrict__ vW2,
                       const float* __restrict__ eW1, const float* __restrict__ eW2,
                       const float* __restrict__ mW,
                       const float* __restrict__ vb1, const float* __restrict__ vb2,
                       const float* __restrict__ eb1, const float* __restrict__ eb2,
                       const float* __restrict__ mb, float* __restrict__ wb,
                       int* __restrict__ deg) {
    int blk = blockIdx.x, t = threadIdx.x;
    if (blk < 436) {
        int i = blk * 256 + t;
        if (i >= W_TOTAL) return;
        float v;
        if (i < W_VW2T)      { int q = i;          int k = q / 128, j = q % 128; v = vW1[(long)j * AD + k]; }
        else if (i < W_EW1T) { int q = i - W_VW2T; int k = q / 128, j = q % 128; v = vW2[(long)j * HD + k]; }
        else if (i < W_EW2T) { int q = i - W_EW1T; int k = q / 128, j = q % 128; v = eW1[(long)j * BD + k]; }
        else if (i < W_MWT)  { int q = i - W_EW2T; int k = q / 128, j = q % 128; v = eW2[(long)j * HD + k]; }
        else if (i < W_VB1)  { int q = i - W_MWT;  int l = q / 16384, r = q % 16384;
                               int k = r / 128, j = r % 128;
                               v = mW[(long)l * 16384 + (long)j * HD + k]; }
        else if (i < W_VB2)  v = vb1[i - W_VB1];
        else if (i < W_EB1)  v = vb2[i - W_VB2];
        else if (i < W_EB2)  v = eb1[i - W_EB1];
        else if (i < W_MB)   v = eb2[i - W_EB2];
        else                 v = mb[i - W_MB];
        wb[i] = v;
    } else {
        int i = (blk - 436) * 256 + t;
        if (i < NV) deg[i] = 0;
    }
}

// micro-GEMM (proven r3/r6-r12)
template<int K>
__device__ __forceinline__ float4 gemm_row(const float* __restrict__ xrow,
                                           const float* __restrict__ Wt, int jg) {
    float4 c = make_float4(0.f, 0.f, 0.f, 0.f);
    const float4* W4 = (const float4*)Wt;
#pragma unroll 8
    for (int k = 0; k < K; k += 4) {
        float4 xv = *(const float4*)(xrow + k);
        float4 w0 = W4[(k + 0) * 32 + jg];
        float4 w1 = W4[(k + 1) * 32 + jg];
        float4 w2 = W4[(k + 2) * 32 + jg];
        float4 w3 = W4[(k + 3) * 32 + jg];
        c.x = fmaf(xv.x, w0.x, fmaf(xv.y, w1.x, fmaf(xv.z, w2.x, fmaf(xv.w, w3.x, c.x))));
        c.y = fmaf(xv.x, w0.y, fmaf(xv.y, w1.y, fmaf(xv.z, w2.y, fmaf(xv.w, w3.y, c.y))));
        c.z = fmaf(xv.x, w0.z, fmaf(xv.y, w1.z, fmaf(xv.z, w2.z, fmaf(xv.w, w3.z, c.z))));
        c.w = fmaf(xv.x, w0.w, fmaf(xv.y, w1.w, fmaf(xv.z, w2.w, fmaf(xv.w, w3.w, c.w))));
    }
    return c;
}

// ---------------------------------------------------------------------------
// dispatch 2 (r12 body + ROLE INTERLEAVE):
// HW dispatches blocks in index order, so r12's [extract...][mlp...] layout
// serialized the MLP work at the tail (+35 us). Interleave 4:3 so every CU
// holds a mix from t=0; MLP blocks retire in us and cycle through while the
// extract wall stands -> MLP hides inside the wall.
//   g%7 < 4 -> extract chunk (g/7)*4 + g%7     (512*4 = 2048)
//   g%7 >= 4 -> mlp unit    (g/7)*3 + g%7 - 4  (512*3 = 1536)
// ---------------------------------------------------------------------------
__global__ __launch_bounds__(256, 3)
void fused_k(const uint4* __restrict__ vew1, const uint4* __restrict__ vew2,
             int* __restrict__ srcv, int* __restrict__ dstv,
             int* __restrict__ deg, int* __restrict__ adj,
             const float* __restrict__ atom, const float* __restrict__ bond,
             const float* __restrict__ wb,
             float* __restrict__ hv, float* __restrict__ outf) {
    __shared__ __align__(16) float xs[8 * AD];   // 2 KB
    __shared__ __align__(16) float t1[8 * HD];   // 4 KB
    int g = blockIdx.x, t = threadIdx.x;
    int grp = g / 7, rem = g % 7;
    if (rem < 4) {
        int blk = grp * 4 + rem;                 // extract chunk 0..2047
        bool isv1 = (blk < 1024);
        const uint4* m = isv1 ? vew1 : vew2;
        int* out = isv1 ? srcv : dstv;
        int r0 = (blk & 1023) * 4;
        const uint4* p = m + (long)r0 * 2048;
#pragma unroll
        for (int b = 0; b < 2; b++) {
            uint4 u[16];
            unsigned o[16];
            int base = b * 4096 + t;
#pragma unroll
            for (int k = 0; k < 16; k++) u[k] = p[base + k * 256];
#pragma unroll
            for (int k = 0; k < 16; k++) o[k] = u[k].x | u[k].y | u[k].z | u[k].w;
            unsigned any = 0;
#pragma unroll
            for (int k = 0; k < 16; k++) any |= o[k];
            if (any == 0u) continue;
#pragma unroll
            for (int k = 0; k < 16; k++) {
                if (o[k] == 0u) continue;
                int i = base + k * 256;
                int row = r0 + (i >> 11);
                int col = (i << 2) & (NE - 1);
#pragma unroll
                for (int q = 0; q < 4; q++) {
                    unsigned val = (q == 0) ? u[k].x : (q == 1) ? u[k].y
                                 : (q == 2) ? u[k].z : u[k].w;
                    if (val) {
                        int e = col + q;
                        out[e] = row;
                        if (isv1) {
                            int pp = atomicAdd(&deg[row], 1);
                            if (pp < DEGCAP) adj[row * DEGCAP + pp] = e;
                        }
                    }
                }
            }
        }
    } else {
        int mu = grp * 3 + (rem - 4);            // mlp unit 0..1535
        int jg = t & 31, rg = t >> 5, j0 = jg * 4;
        if (mu < 512) {
            // node input MLP, 8 rows -> hvA
            int r0 = mu * 8;
            for (int i = t; i < 8 * AD; i += 256) xs[i] = atom[(long)r0 * AD + i];
            __syncthreads();
            float4 c1 = gemm_row<AD>(xs + rg * AD, wb + W_VW1T, jg);
            float4 b1 = *(const float4*)(wb + W_VB1 + j0);
            c1.x = leaky(c1.x + b1.x); c1.y = leaky(c1.y + b1.y);
            c1.z = leaky(c1.z + b1.z); c1.w = leaky(c1.w + b1.w);
            *(float4*)(t1 + rg * HD + j0) = c1;
            __syncthreads();
            float4 c2 = gemm_row<HD>(t1 + rg * HD, wb + W_VW2T, jg);
            float4 b2 = *(const float4*)(wb + W_VB2 + j0);
            c2.x = tanhf(c2.x + b2.x); c2.y = tanhf(c2.y + b2.y);
            c2.z = tanhf(c2.z + b2.z); c2.w = tanhf(c2.w + b2.w);
            *(float4*)(hv + (long)(r0 + rg) * HD + j0) = c2;
        } else {
            // edge input MLP, 8 rows -> he out slot
            int r0 = (mu - 512) * 8;
            if (t < 8 * BD) xs[t] = bond[(long)r0 * BD + t];
            __syncthreads();
            float4 c1 = gemm_row<BD>(xs + rg * BD, wb + W_EW1T, jg);
            float4 b1 = *(const float4*)(wb + W_EB1 + j0);
            c1.x = leaky(c1.x + b1.x); c1.y = leaky(c1.y + b1.y);
            c1.z = leaky(c1.z + b1.z); c1.w = leaky(c1.w + b1.w);
            *(float4*)(t1 + rg * HD + j0) = c1;
            __syncthreads();
            float4 c2 = gemm_row<HD>(t1 + rg * HD, wb + W_EW2T, jg);
            float4 b2 = *(const float4*)(wb + W_EB2 + j0);
            c2.x = tanhf(c2.x + b2.x); c2.y = tanhf(c2.y + b2.y);
            c2.z = tanhf(c2.z + b2.z); c2.w = tanhf(c2.w + b2.w);
            *(float4*)(outf + (long)OUT_HE + (long)(r0 + rg) * ESTR + 2 * HD + j0) = c2;
        }
    }
}

// fused layer (r11/r12-proven verbatim): gather + MLP, no atomics
__global__ void layer_k(const float* __restrict__ hvin, const float* __restrict__ wb,
                        const int* __restrict__ deg, const int* __restrict__ adj,
                        const int* __restrict__ dstv, const float* __restrict__ outf,
                        float* __restrict__ hvout, int l, float* hv_out) {
    __shared__ __align__(16) float xs[4 * HD];
    int t = threadIdx.x, jg = t & 31, rg = t >> 5, j0 = jg * 4;
    int r = blockIdx.x * 4 + rg;
    float4 x = *(const float4*)(hvin + (long)r * HD + j0);
    int dn = min(deg[r], DEGCAP);
    const int* al = adj + r * DEGCAP;
    for (int i = 0; i < dn; i++) {
        int e = al[i]; e = max(0, min(e, NE - 1));
        int d = clampv(dstv[e]);
        float4 he = *(const float4*)(outf + (long)OUT_HE + (long)e * ESTR + 2 * HD + j0);
        float4 hd = *(const float4*)(hvin + (long)d * HD + j0);
        float s0 = he.x + hd.x, s1 = he.y + hd.y;
        float s2 = he.z + hd.z, s3 = he.w + hd.w;
        x.x += s0 > 0.f ? s0 : 0.f; x.y += s1 > 0.f ? s1 : 0.f;
        x.z += s2 > 0.f ? s2 : 0.f; x.w += s3 > 0.f ? s3 : 0.f;
    }
    *(float4*)(xs + rg * HD + j0) = x;
    __syncthreads();
    float4 c = gemm_row<HD>(xs + rg * HD, wb + W_MWT + l * 16384, jg);
    float4 b = *(const float4*)(wb + W_MB + l * HD + j0);
    c.x = leaky(c.x + b.x); c.y = leaky(c.y + b.y);
    c.z = leaky(c.z + b.z); c.w = leaky(c.w + b.w);
    long o = (long)r * HD + j0;
    *(float4*)(hvout + o) = c;
    if (hv_out) *(float4*)(hv_out + o) = c;
}

// gather sections (proven verbatim)
__global__ void out_he_k(const float* __restrict__ hv,
                         const int* __restrict__ src, const int* __restrict__ dst,
                         float* __restrict__ outf) {
    int e = blockIdx.x, t = threadIdx.x, j0 = t * 2;
    int s = clampv(src[e]), d = clampv(dst[e]);
    float2 a = *(const float2*)(hv + (long)s * HD + j0);
    float2 b = *(const float2*)(hv + (long)d * HD + j0);
    float* base = outf + (long)OUT_HE + (long)e * ESTR;
    *(float2*)(base + j0) = a;
    *(float2*)(base + HD + j0) = b;
}

extern "C" void kernel_launch(void* const* d_in, const int* in_sizes, int n_in,
                              void* d_out, int out_size, void* d_ws, size_t ws_size,
                              hipStream_t stream) {
    char* ws = (char*)d_ws;
    int*   srcv = (int*)(ws + WS_SRC);
    int*   dstv = (int*)(ws + WS_DST);
    int*   deg  = (int*)(ws + WS_DEG);
    int*   adj  = (int*)(ws + WS_ADJ);
    float* wb   = (float*)(ws + WS_WB);
    float* hvA  = (float*)(ws + WS_HVA);
    float* hvB  = (float*)(ws + WS_HVB);
    float* outf = (float*)d_out;

    prep_k<<<452, 256, 0, stream>>>(
        (const float*)d_in[4], (const float*)d_in[6], (const float*)d_in[8],
        (const float*)d_in[10], (const float*)d_in[12],
        (const float*)d_in[5], (const float*)d_in[7], (const float*)d_in[9],
        (const float*)d_in[11], (const float*)d_in[13], wb, deg);

    fused_k<<<3584, 256, 0, stream>>>(
        (const uint4*)d_in[2], (const uint4*)d_in[3], srcv, dstv, deg, adj,
        (const float*)d_in[0], (const float*)d_in[1], wb, hvA, outf);

    // ping-pong: A->B->A->B->A (final hv in A)
    layer_k<<<NV / 4, 128, 0, stream>>>(hvA, wb, deg, adj, dstv, outf, hvB, 0, nullptr);
    layer_k<<<NV / 4, 128, 0, stream>>>(hvB, wb, deg, adj, dstv, outf, hvA, 1, nullptr);
    layer_k<<<NV / 4, 128, 0, stream>>>(hvA, wb, deg, adj, dstv, outf, hvB, 2, nullptr);
    layer_k<<<NV / 4, 128, 0, stream>>>(hvB, wb, deg, adj, dstv, outf, hvA, 3, outf);

    out_he_k<<<NE, 64, 0, stream>>>(hvA, srcv, dstv, outf);
}

// Round 14
// 369.262 us; speedup vs baseline: 1.1834x; 1.1121x over previous
//
#include <hip/hip_runtime.h>
#include <hip/hip_bf16.h>

#define NV 4096
#define NE 8192
#define AD 64      // ATOM_DIM
#define BD 32      // BOND_DIM_P1
#define HD 128     // H
#define NL 4       // N_LAYER
#define DEGCAP 32  // adjacency bucket capacity (lambda=2 Poisson, max deg << 32)

// Everything is fp32 (proven r6-r13).

typedef unsigned int v4u __attribute__((ext_vector_type(4)));

__device__ __forceinline__ float leaky(float x) { return x > 0.f ? x : 0.01f * x; }
__device__ __forceinline__ int clampv(int x) { return min(max(x, 0), NV - 1); }

// ---- fp32 weight scratch layout (float offsets), proven r3/r6-r13 ----
#define W_VW1T 0           // [64][128]   Wt[k][j] = W[j][k]
#define W_VW2T 8192        // [128][128]
#define W_EW1T 24576       // [32][128]
#define W_EW2T 28672       // [128][128]
#define W_MWT  45056       // [4][128][128]
#define W_VB1  110592
#define W_VB2  110720
#define W_EB1  110848
#define W_EB2  110976
#define W_MB   111104      // [4][128]
#define W_TOTAL 111616     // = 436 * 256 exactly

// ---- out layout (float offsets): [hv 524288][per-edge 384: src|dst|he] ----
#define OUT_HE 524288
#define ESTR   384

// ---- ws layout (byte offsets) ----
#define WS_SRC  0            // NE ints
#define WS_DST  32768        // NE ints
#define WS_DEGS 65536        // NV ints
#define WS_ADJS 81920        // NV*DEGCAP ints (512 KB)
#define WS_DEGD 606208       // NV ints
#define WS_ADJD 622592       // NV*DEGCAP ints (512 KB)
#define WS_WB   1146880      // W_TOTAL floats
#define WS_HVA  1593344      // NV*HD floats (2 MB)
#define WS_HVB  3690496      // NV*HD floats (2 MB)

// ---------------------------------------------------------------------------
// dispatch 1 (tiny): weight transpose + bias copy (proven map) + both deg = 0
// blocks [0,436): weights; [436,468): degS,degD zero (2*NV ints)
// ---------------------------------------------------------------------------
__global__ void prep_k(const float* __restrict__ vW1, const float* __restrict__ vW2,
                       const float* __restrict__ eW1, const float* __restrict__ eW2,
                       const float* __restrict__ mW,
                       const float* __restrict__ vb1, const float* __restrict__ vb2,
                       const float* __restrict__ eb1, const float* __restrict__ eb2,
                       const float* __restrict__ mb, float* __restrict__ wb,
                       int* __restrict__ degS, int* __restrict__ degD) {
    int blk = blockIdx.x, t = threadIdx.x;
    if (blk < 436) {
        int i = blk * 256 + t;
        if (i >= W_TOTAL) return;
        float v;
        if (i < W_VW2T)      { int q = i;          int k = q / 128, j = q % 128; v = vW1[(long)j * AD + k]; }
        else if (i < W_EW1T) { int q = i - W_VW2T; int k = q / 128, j = q % 128; v = vW2[(long)j * HD + k]; }
        else if (i < W_EW2T) { int q = i - W_EW1T; int k = q / 128, j = q % 128; v = eW1[(long)j * BD + k]; }
        else if (i < W_MWT)  { int q = i - W_EW2T; int k = q / 128, j = q % 128; v = eW2[(long)j * HD + k]; }
        else if (i < W_VB1)  { int q = i - W_MWT;  int l = q / 16384, r = q % 16384;
                               int k = r / 128, j = r % 128;
                               v = mW[(long)l * 16384 + (long)j * HD + k]; }
        else if (i < W_VB2)  v = vb1[i - W_VB1];
        else if (i < W_EB1)  v = vb2[i - W_VB2];
        else if (i < W_EB2)  v = eb1[i - W_EB1];
        else if (i < W_MB)   v = eb2[i - W_EB2];
        else                 v = mb[i - W_MB];
        wb[i] = v;
    } else {
        int i = (blk - 436) * 256 + t;
        if (i < NV) degS[i] = 0;
        else if (i < 2 * NV) degD[i - NV] = 0;
    }
}

// micro-GEMM (proven r3/r6-r13)
template<int K>
__device__ __forceinline__ float4 gemm_row(const float* __restrict__ xrow,
                                           const float* __restrict__ Wt, int jg) {
    float4 c = make_float4(0.f, 0.f, 0.f, 0.f);
    const float4* W4 = (const float4*)Wt;
#pragma unroll 8
    for (int k = 0; k < K; k += 4) {
        float4 xv = *(const float4*)(xrow + k);
        float4 w0 = W4[(k + 0) * 32 + jg];
        float4 w1 = W4[(k + 1) * 32 + jg];
        float4 w2 = W4[(k + 2) * 32 + jg];
        float4 w3 = W4[(k + 3) * 32 + jg];
        c.x = fmaf(xv.x, w0.x, fmaf(xv.y, w1.x, fmaf(xv.z, w2.x, fmaf(xv.w, w3.x, c.x))));
        c.y = fmaf(xv.x, w0.y, fmaf(xv.y, w1.y, fmaf(xv.z, w2.y, fmaf(xv.w, w3.y, c.y))));
        c.z = fmaf(xv.x, w0.z, fmaf(xv.y, w1.z, fmaf(xv.z, w2.z, fmaf(xv.w, w3.z, c.z))));
        c.w = fmaf(xv.x, w0.w, fmaf(xv.y, w1.w, fmaf(xv.z, w2.w, fmaf(xv.w, w3.w, c.w))));
    }
    return c;
}

// ---------------------------------------------------------------------------
// dispatch 2 (r13-proven interleave 4:3; extract now nontemporal + fills BOTH
// adjacencies in the rare path):
//   g%7 < 4 -> extract chunk (g/7)*4 + g%7     (512*4 = 2048)
//   g%7 >= 4 -> mlp unit    (g/7)*3 + g%7 - 4  (512*3 = 1536)
// ---------------------------------------------------------------------------
__global__ __launch_bounds__(256, 3)
void fused_k(const v4u* __restrict__ vew1, const v4u* __restrict__ vew2,
             int* __restrict__ srcv, int* __restrict__ dstv,
             int* __restrict__ degS, int* __restrict__ adjS,
             int* __restrict__ degD, int* __restrict__ adjD,
             const float* __restrict__ atom, const float* __restrict__ bond,
             const float* __restrict__ wb,
             float* __restrict__ hv, float* __restrict__ outf) {
    __shared__ __align__(16) float xs[8 * AD];   // 2 KB
    __shared__ __align__(16) float t1[8 * HD];   // 4 KB
    int g = blockIdx.x, t = threadIdx.x;
    int grp = g / 7, rem = g % 7;
    if (rem < 4) {
        int blk = grp * 4 + rem;                 // extract chunk 0..2047
        bool isv1 = (blk < 1024);
        const v4u* m = isv1 ? vew1 : vew2;
        int* out = isv1 ? srcv : dstv;
        int* deg = isv1 ? degS : degD;
        int* adj = isv1 ? adjS : adjD;
        int r0 = (blk & 1023) * 4;
        const v4u* p = m + (long)r0 * 2048;
#pragma unroll
        for (int b = 0; b < 2; b++) {
            v4u u[16];
            unsigned o[16];
            int base = b * 4096 + t;
#pragma unroll
            for (int k = 0; k < 16; k++) u[k] = __builtin_nontemporal_load(&p[base + k * 256]);
#pragma unroll
            for (int k = 0; k < 16; k++) o[k] = u[k].x | u[k].y | u[k].z | u[k].w;
            unsigned any = 0;
#pragma unroll
            for (int k = 0; k < 16; k++) any |= o[k];
            if (any == 0u) continue;
#pragma unroll
            for (int k = 0; k < 16; k++) {
                if (o[k] == 0u) continue;
                int i = base + k * 256;
                int row = r0 + (i >> 11);
                int col = (i << 2) & (NE - 1);
#pragma unroll
                for (int q = 0; q < 4; q++) {
                    unsigned val = (q == 0) ? u[k].x : (q == 1) ? u[k].y
                                 : (q == 2) ? u[k].z : u[k].w;
                    if (val) {
                        int e = col + q;
                        out[e] = row;
                        int pp = atomicAdd(&deg[row], 1);
                        if (pp < DEGCAP) adj[row * DEGCAP + pp] = e;
                    }
                }
            }
        }
    } else {
        int mu = grp * 3 + (rem - 4);            // mlp unit 0..1535
        int jg = t & 31, rg = t >> 5, j0 = jg * 4;
        if (mu < 512) {
            // node input MLP, 8 rows -> hvA
            int r0 = mu * 8;
            for (int i = t; i < 8 * AD; i += 256) xs[i] = atom[(long)r0 * AD + i];
            __syncthreads();
            float4 c1 = gemm_row<AD>(xs + rg * AD, wb + W_VW1T, jg);
            float4 b1 = *(const float4*)(wb + W_VB1 + j0);
            c1.x = leaky(c1.x + b1.x); c1.y = leaky(c1.y + b1.y);
            c1.z = leaky(c1.z + b1.z); c1.w = leaky(c1.w + b1.w);
            *(float4*)(t1 + rg * HD + j0) = c1;
            __syncthreads();
            float4 c2 = gemm_row<HD>(t1 + rg * HD, wb + W_VW2T, jg);
            float4 b2 = *(const float4*)(wb + W_VB2 + j0);
            c2.x = tanhf(c2.x + b2.x); c2.y = tanhf(c2.y + b2.y);
            c2.z = tanhf(c2.z + b2.z); c2.w = tanhf(c2.w + b2.w);
            *(float4*)(hv + (long)(r0 + rg) * HD + j0) = c2;
        } else {
            // edge input MLP, 8 rows -> he out slot
            int r0 = (mu - 512) * 8;
            if (t < 8 * BD) xs[t] = bond[(long)r0 * BD + t];
            __syncthreads();
            float4 c1 = gemm_row<BD>(xs + rg * BD, wb + W_EW1T, jg);
            float4 b1 = *(const float4*)(wb + W_EB1 + j0);
            c1.x = leaky(c1.x + b1.x); c1.y = leaky(c1.y + b1.y);
            c1.z = leaky(c1.z + b1.z); c1.w = leaky(c1.w + b1.w);
            *(float4*)(t1 + rg * HD + j0) = c1;
            __syncthreads();
            float4 c2 = gemm_row<HD>(t1 + rg * HD, wb + W_EW2T, jg);
            float4 b2 = *(const float4*)(wb + W_EB2 + j0);
            c2.x = tanhf(c2.x + b2.x); c2.y = tanhf(c2.y + b2.y);
            c2.z = tanhf(c2.z + b2.z); c2.w = tanhf(c2.w + b2.w);
            *(float4*)(outf + (long)OUT_HE + (long)(r0 + rg) * ESTR + 2 * HD + j0) = c2;
        }
    }
}

// ---------------------------------------------------------------------------
// fused layer (r11-r13-proven gather + MLP). On l==3 (hv_out != null) each
// row-group also SCATTERS its finished row into the per-edge gather sections:
//   e in adjS(r): out[OUT_HE + e*384 +   0 + j] = hv[r][j]   (src section)
//   e in adjD(r): out[OUT_HE + e*384 + 128 + j] = hv[r][j]   (dst section)
// Every edge has exactly one src + one dst -> full coverage, no races.
// This replaces the separate out_he_k dispatch.
// ---------------------------------------------------------------------------
__global__ void layer_k(const float* __restrict__ hvin, const float* __restrict__ wb,
                        const int* __restrict__ degS, const int* __restrict__ adjS,
                        const int* __restrict__ degD, const int* __restrict__ adjD,
                        const int* __restrict__ dstv, const float* __restrict__ outf,
                        float* __restrict__ hvout, int l, float* hv_out,
                        float* __restrict__ outw) {
    __shared__ __align__(16) float xs[4 * HD];
    int t = threadIdx.x, jg = t & 31, rg = t >> 5, j0 = jg * 4;
    int r = blockIdx.x * 4 + rg;
    float4 x = *(const float4*)(hvin + (long)r * HD + j0);
    int dnS = min(degS[r], DEGCAP);
    const int* alS = adjS + r * DEGCAP;
    for (int i = 0; i < dnS; i++) {
        int e = alS[i]; e = max(0, min(e, NE - 1));
        int d = clampv(dstv[e]);
        float4 he = *(const float4*)(outf + (long)OUT_HE + (long)e * ESTR + 2 * HD + j0);
        float4 hd = *(const float4*)(hvin + (long)d * HD + j0);
        float s0 = he.x + hd.x, s1 = he.y + hd.y;
        float s2 = he.z + hd.z, s3 = he.w + hd.w;
        x.x += s0 > 0.f ? s0 : 0.f; x.y += s1 > 0.f ? s1 : 0.f;
        x.z += s2 > 0.f ? s2 : 0.f; x.w += s3 > 0.f ? s3 : 0.f;
    }
    *(float4*)(xs + rg * HD + j0) = x;
    __syncthreads();
    float4 c = gemm_row<HD>(xs + rg * HD, wb + W_MWT + l * 16384, jg);
    float4 b = *(const float4*)(wb + W_MB + l * HD + j0);
    c.x = leaky(c.x + b.x); c.y = leaky(c.y + b.y);
    c.z = leaky(c.z + b.z); c.w = leaky(c.w + b.w);
    long o = (long)r * HD + j0;
    *(float4*)(hvout + o) = c;
    if (hv_out) {
        *(float4*)(hv_out + o) = c;                       // out-hv section
        for (int i = 0; i < dnS; i++) {                   // src-gather sections
            int e = alS[i]; e = max(0, min(e, NE - 1));
            *(float4*)(outw + (long)OUT_HE + (long)e * ESTR + j0) = c;
        }
        int dnD = min(degD[r], DEGCAP);
        const int* alD = adjD + r * DEGCAP;
        for (int i = 0; i < dnD; i++) {                   // dst-gather sections
            int e = alD[i]; e = max(0, min(e, NE - 1));
            *(float4*)(outw + (long)OUT_HE + (long)e * ESTR + HD + j0) = c;
        }
    }
}

extern "C" void kernel_launch(void* const* d_in, const int* in_sizes, int n_in,
                              void* d_out, int out_size, void* d_ws, size_t ws_size,
                              hipStream_t stream) {
    char* ws = (char*)d_ws;
    int*   srcv = (int*)(ws + WS_SRC);
    int*   dstv = (int*)(ws + WS_DST);
    int*   degS = (int*)(ws + WS_DEGS);
    int*   adjS = (int*)(ws + WS_ADJS);
    int*   degD = (int*)(ws + WS_DEGD);
    int*   adjD = (int*)(ws + WS_ADJD);
    float* wb   = (float*)(ws + WS_WB);
    float* hvA  = (float*)(ws + WS_HVA);
    float* hvB  = (float*)(ws + WS_HVB);
    float* outf = (float*)d_out;

    prep_k<<<468, 256, 0, stream>>>(
        (const float*)d_in[4], (const float*)d_in[6], (const float*)d_in[8],
        (const float*)d_in[10], (const float*)d_in[12],
        (const float*)d_in[5], (const float*)d_in[7], (const float*)d_in[9],
        (const float*)d_in[11], (const float*)d_in[13], wb, degS, degD);

    fused_k<<<3584, 256, 0, stream>>>(
        (const v4u*)d_in[2], (const v4u*)d_in[3], srcv, dstv,
        degS, adjS, degD, adjD,
        (const float*)d_in[0], (const float*)d_in[1], wb, hvA, outf);

    // ping-pong: A->B->A->B->A; l=3 scatters gather sections (out_he fused away)
    layer_k<<<NV / 4, 128, 0, stream>>>(hvA, wb, degS, adjS, degD, adjD, dstv, outf, hvB, 0, nullptr, outf);
    layer_k<<<NV / 4, 128, 0, stream>>>(hvB, wb, degS, adjS, degD, adjD, dstv, outf, hvA, 1, nullptr, outf);
    layer_k<<<NV / 4, 128, 0, stream>>>(hvA, wb, degS, adjS, degD, adjD, dstv, outf, hvB, 2, nullptr, outf);
    layer_k<<<NV / 4, 128, 0, stream>>>(hvB, wb, degS, adjS, degD, adjD, dstv, outf, hvA, 3, outf, outf);
}

// Round 15
// 364.821 us; speedup vs baseline: 1.1978x; 1.0122x over previous
//
#include <hip/hip_runtime.h>
#include <hip/hip_bf16.h>

#define NV 4096
#define NE 8192
#define AD 64      // ATOM_DIM
#define BD 32      // BOND_DIM_P1
#define HD 128     // H
#define NL 4       // N_LAYER
#define DEGCAP 32  // adjacency bucket capacity (lambda=2 Poisson, max deg << 32)

// Everything is fp32 (proven r6-r14).

typedef unsigned int v4u __attribute__((ext_vector_type(4)));

__device__ __forceinline__ float leaky(float x) { return x > 0.f ? x : 0.01f * x; }
__device__ __forceinline__ int clampv(int x) { return min(max(x, 0), NV - 1); }
__device__ __forceinline__ void nt_store4(float* p, float4 v) {
    __builtin_nontemporal_store(v.x, p);
    __builtin_nontemporal_store(v.y, p + 1);
    __builtin_nontemporal_store(v.z, p + 2);
    __builtin_nontemporal_store(v.w, p + 3);
}

// ---- fp32 weight scratch layout (float offsets), proven r3/r6-r14 ----
#define W_VW1T 0           // [64][128]   Wt[k][j] = W[j][k]
#define W_VW2T 8192        // [128][128]
#define W_EW1T 24576       // [32][128]
#define W_EW2T 28672       // [128][128]
#define W_MWT  45056       // [4][128][128]
#define W_VB1  110592
#define W_VB2  110720
#define W_EB1  110848
#define W_EB2  110976
#define W_MB   111104      // [4][128]
#define W_TOTAL 111616     // = 436 * 256 exactly

// ---- out layout (float offsets): [hv 524288][per-edge 384: src|dst|he] ----
#define OUT_HE 524288
#define ESTR   384

// ---- ws layout (byte offsets), r14-proven ----
#define WS_SRC  0            // NE ints
#define WS_DST  32768        // NE ints
#define WS_DEGS 65536        // NV ints
#define WS_ADJS 81920        // NV*DEGCAP ints (512 KB)
#define WS_DEGD 606208       // NV ints
#define WS_ADJD 622592       // NV*DEGCAP ints (512 KB)
#define WS_WB   1146880      // W_TOTAL floats
#define WS_HVA  1593344      // NV*HD floats (2 MB)
#define WS_HVB  3690496      // NV*HD floats (2 MB)

// ---------------------------------------------------------------------------
// dispatch 1 (tiny, r14-proven): weight transpose + bias copy + both deg = 0
// ---------------------------------------------------------------------------
__global__ void prep_k(const float* __restrict__ vW1, const float* __restrict__ vW2,
                       const float* __restrict__ eW1, const float* __restrict__ eW2,
                       const float* __restrict__ mW,
                       const float* __restrict__ vb1, const float* __restrict__ vb2,
                       const float* __restrict__ eb1, const float* __restrict__ eb2,
                       const float* __restrict__ mb, float* __restrict__ wb,
                       int* __restrict__ degS, int* __restrict__ degD) {
    int blk = blockIdx.x, t = threadIdx.x;
    if (blk < 436) {
        int i = blk * 256 + t;
        if (i >= W_TOTAL) return;
        float v;
        if (i < W_VW2T)      { int q = i;          int k = q / 128, j = q % 128; v = vW1[(long)j * AD + k]; }
        else if (i < W_EW1T) { int q = i - W_VW2T; int k = q / 128, j = q % 128; v = vW2[(long)j * HD + k]; }
        else if (i < W_EW2T) { int q = i - W_EW1T; int k = q / 128, j = q % 128; v = eW1[(long)j * BD + k]; }
        else if (i < W_MWT)  { int q = i - W_EW2T; int k = q / 128, j = q % 128; v = eW2[(long)j * HD + k]; }
        else if (i < W_VB1)  { int q = i - W_MWT;  int l = q / 16384, r = q % 16384;
                               int k = r / 128, j = r % 128;
                               v = mW[(long)l * 16384 + (long)j * HD + k]; }
        else if (i < W_VB2)  v = vb1[i - W_VB1];
        else if (i < W_EB1)  v = vb2[i - W_VB2];
        else if (i < W_EB2)  v = eb1[i - W_EB1];
        else if (i < W_MB)   v = eb2[i - W_EB2];
        else                 v = mb[i - W_MB];
        wb[i] = v;
    } else {
        int i = (blk - 436) * 256 + t;
        if (i < NV) degS[i] = 0;
        else if (i < 2 * NV) degD[i - NV] = 0;
    }
}

// micro-GEMM (proven r3/r6-r14)
template<int K>
__device__ __forceinline__ float4 gemm_row(const float* __restrict__ xrow,
                                           const float* __restrict__ Wt, int jg) {
    float4 c = make_float4(0.f, 0.f, 0.f, 0.f);
    const float4* W4 = (const float4*)Wt;
#pragma unroll 8
    for (int k = 0; k < K; k += 4) {
        float4 xv = *(const float4*)(xrow + k);
        float4 w0 = W4[(k + 0) * 32 + jg];
        float4 w1 = W4[(k + 1) * 32 + jg];
        float4 w2 = W4[(k + 2) * 32 + jg];
        float4 w3 = W4[(k + 3) * 32 + jg];
        c.x = fmaf(xv.x, w0.x, fmaf(xv.y, w1.x, fmaf(xv.z, w2.x, fmaf(xv.w, w3.x, c.x))));
        c.y = fmaf(xv.x, w0.y, fmaf(xv.y, w1.y, fmaf(xv.z, w2.y, fmaf(xv.w, w3.y, c.y))));
        c.z = fmaf(xv.x, w0.z, fmaf(xv.y, w1.z, fmaf(xv.z, w2.z, fmaf(xv.w, w3.z, c.z))));
        c.w = fmaf(xv.x, w0.w, fmaf(xv.y, w1.w, fmaf(xv.z, w2.w, fmaf(xv.w, w3.w, c.w))));
    }
    return c;
}

// ---------------------------------------------------------------------------
// dispatch 2 (r14-proven: interleave 4:3, nt incidence loads, dual adjacency;
// NEW: nt loads for read-once atom/bond so they don't evict weights/he in L2)
// ---------------------------------------------------------------------------
__global__ __launch_bounds__(256, 3)
void fused_k(const v4u* __restrict__ vew1, const v4u* __restrict__ vew2,
             int* __restrict__ srcv, int* __restrict__ dstv,
             int* __restrict__ degS, int* __restrict__ adjS,
             int* __restrict__ degD, int* __restrict__ adjD,
             const float* __restrict__ atom, const float* __restrict__ bond,
             const float* __restrict__ wb,
             float* __restrict__ hv, float* __restrict__ outf) {
    __shared__ __align__(16) float xs[8 * AD];   // 2 KB
    __shared__ __align__(16) float t1[8 * HD];   // 4 KB
    int g = blockIdx.x, t = threadIdx.x;
    int grp = g / 7, rem = g % 7;
    if (rem < 4) {
        int blk = grp * 4 + rem;                 // extract chunk 0..2047
        bool isv1 = (blk < 1024);
        const v4u* m = isv1 ? vew1 : vew2;
        int* out = isv1 ? srcv : dstv;
        int* deg = isv1 ? degS : degD;
        int* adj = isv1 ? adjS : adjD;
        int r0 = (blk & 1023) * 4;
        const v4u* p = m + (long)r0 * 2048;
#pragma unroll
        for (int b = 0; b < 2; b++) {
            v4u u[16];
            unsigned o[16];
            int base = b * 4096 + t;
#pragma unroll
            for (int k = 0; k < 16; k++) u[k] = __builtin_nontemporal_load(&p[base + k * 256]);
#pragma unroll
            for (int k = 0; k < 16; k++) o[k] = u[k].x | u[k].y | u[k].z | u[k].w;
            unsigned any = 0;
#pragma unroll
            for (int k = 0; k < 16; k++) any |= o[k];
            if (any == 0u) continue;
#pragma unroll
            for (int k = 0; k < 16; k++) {
                if (o[k] == 0u) continue;
                int i = base + k * 256;
                int row = r0 + (i >> 11);
                int col = (i << 2) & (NE - 1);
#pragma unroll
                for (int q = 0; q < 4; q++) {
                    unsigned val = (q == 0) ? u[k].x : (q == 1) ? u[k].y
                                 : (q == 2) ? u[k].z : u[k].w;
                    if (val) {
                        int e = col + q;
                        out[e] = row;
                        int pp = atomicAdd(&deg[row], 1);
                        if (pp < DEGCAP) adj[row * DEGCAP + pp] = e;
                    }
                }
            }
        }
    } else {
        int mu = grp * 3 + (rem - 4);            // mlp unit 0..1535
        int jg = t & 31, rg = t >> 5, j0 = jg * 4;
        if (mu < 512) {
            // node input MLP, 8 rows -> hvA
            int r0 = mu * 8;
            for (int i = t; i < 8 * AD; i += 256)
                xs[i] = __builtin_nontemporal_load(&atom[(long)r0 * AD + i]);
            __syncthreads();
            float4 c1 = gemm_row<AD>(xs + rg * AD, wb + W_VW1T, jg);
            float4 b1 = *(const float4*)(wb + W_VB1 + j0);
            c1.x = leaky(c1.x + b1.x); c1.y = leaky(c1.y + b1.y);
            c1.z = leaky(c1.z + b1.z); c1.w = leaky(c1.w + b1.w);
            *(float4*)(t1 + rg * HD + j0) = c1;
            __syncthreads();
            float4 c2 = gemm_row<HD>(t1 + rg * HD, wb + W_VW2T, jg);
            float4 b2 = *(const float4*)(wb + W_VB2 + j0);
            c2.x = tanhf(c2.x + b2.x); c2.y = tanhf(c2.y + b2.y);
            c2.z = tanhf(c2.z + b2.z); c2.w = tanhf(c2.w + b2.w);
            *(float4*)(hv + (long)(r0 + rg) * HD + j0) = c2;
        } else {
            // edge input MLP, 8 rows -> he out slot (re-read by layers: cached)
            int r0 = (mu - 512) * 8;
            if (t < 8 * BD) xs[t] = __builtin_nontemporal_load(&bond[(long)r0 * BD + t]);
            __syncthreads();
            float4 c1 = gemm_row<BD>(xs + rg * BD, wb + W_EW1T, jg);
            float4 b1 = *(const float4*)(wb + W_EB1 + j0);
            c1.x = leaky(c1.x + b1.x); c1.y = leaky(c1.y + b1.y);
            c1.z = leaky(c1.z + b1.z); c1.w = leaky(c1.w + b1.w);
            *(float4*)(t1 + rg * HD + j0) = c1;
            __syncthreads();
            float4 c2 = gemm_row<HD>(t1 + rg * HD, wb + W_EW2T, jg);
            float4 b2 = *(const float4*)(wb + W_EB2 + j0);
            c2.x = tanhf(c2.x + b2.x); c2.y = tanhf(c2.y + b2.y);
            c2.z = tanhf(c2.z + b2.z); c2.w = tanhf(c2.w + b2.w);
            *(float4*)(outf + (long)OUT_HE + (long)(r0 + rg) * ESTR + 2 * HD + j0) = c2;
        }
    }
}

// ---------------------------------------------------------------------------
// fused layer (r14-proven). Final-output writes (l==3) now nontemporal:
// they are never re-read on device -> no L2 allocation/RFO.
// ---------------------------------------------------------------------------
__global__ void layer_k(const float* __restrict__ hvin, const float* __restrict__ wb,
                        const int* __restrict__ degS, const int* __restrict__ adjS,
                        const int* __restrict__ degD, const int* __restrict__ adjD,
                        const int* __restrict__ dstv, const float* __restrict__ outf,
                        float* __restrict__ hvout, int l, float* hv_out,
                        float* __restrict__ outw) {
    __shared__ __align__(16) float xs[4 * HD];
    int t = threadIdx.x, jg = t & 31, rg = t >> 5, j0 = jg * 4;
    int r = blockIdx.x * 4 + rg;
    float4 x = *(const float4*)(hvin + (long)r * HD + j0);
    int dnS = min(degS[r], DEGCAP);
    const int* alS = adjS + r * DEGCAP;
    for (int i = 0; i < dnS; i++) {
        int e = alS[i]; e = max(0, min(e, NE - 1));
        int d = clampv(dstv[e]);
        float4 he = *(const float4*)(outf + (long)OUT_HE + (long)e * ESTR + 2 * HD + j0);
        float4 hd = *(const float4*)(hvin + (long)d * HD + j0);
        float s0 = he.x + hd.x, s1 = he.y + hd.y;
        float s2 = he.z + hd.z, s3 = he.w + hd.w;
        x.x += s0 > 0.f ? s0 : 0.f; x.y += s1 > 0.f ? s1 : 0.f;
        x.z += s2 > 0.f ? s2 : 0.f; x.w += s3 > 0.f ? s3 : 0.f;
    }
    *(float4*)(xs + rg * HD + j0) = x;
    __syncthreads();
    float4 c = gemm_row<HD>(xs + rg * HD, wb + W_MWT + l * 16384, jg);
    float4 b = *(const float4*)(wb + W_MB + l * HD + j0);
    c.x = leaky(c.x + b.x); c.y = leaky(c.y + b.y);
    c.z = leaky(c.z + b.z); c.w = leaky(c.w + b.w);
    long o = (long)r * HD + j0;
    *(float4*)(hvout + o) = c;
    if (hv_out) {
        nt_store4(hv_out + o, c);                         // out-hv section
        for (int i = 0; i < dnS; i++) {                   // src-gather sections
            int e = alS[i]; e = max(0, min(e, NE - 1));
            nt_store4(outw + (long)OUT_HE + (long)e * ESTR + j0, c);
        }
        int dnD = min(degD[r], DEGCAP);
        const int* alD = adjD + r * DEGCAP;
        for (int i = 0; i < dnD; i++) {                   // dst-gather sections
            int e = alD[i]; e = max(0, min(e, NE - 1));
            nt_store4(outw + (long)OUT_HE + (long)e * ESTR + HD + j0, c);
        }
    }
}

extern "C" void kernel_launch(void* const* d_in, const int* in_sizes, int n_in,
                              void* d_out, int out_size, void* d_ws, size_t ws_size,
                              hipStream_t stream) {
    char* ws = (char*)d_ws;
    int*   srcv = (int*)(ws + WS_SRC);
    int*   dstv = (int*)(ws + WS_DST);
    int*   degS = (int*)(ws + WS_DEGS);
    int*   adjS = (int*)(ws + WS_ADJS);
    int*   degD = (int*)(ws + WS_DEGD);
    int*   adjD = (int*)(ws + WS_ADJD);
    float* wb   = (float*)(ws + WS_WB);
    float* hvA  = (float*)(ws + WS_HVA);
    float* hvB  = (float*)(ws + WS_HVB);
    float* outf = (float*)d_out;

    prep_k<<<468, 256, 0, stream>>>(
        (const float*)d_in[4], (const float*)d_in[6], (const float*)d_in[8],
        (const float*)d_in[10], (const float*)d_in[12],
        (const float*)d_in[5], (const float*)d_in[7], (const float*)d_in[9],
        (const float*)d_in[11], (const float*)d_in[13], wb, degS, degD);

    fused_k<<<3584, 256, 0, stream>>>(
        (const v4u*)d_in[2], (const v4u*)d_in[3], srcv, dstv,
        degS, adjS, degD, adjD,
        (const float*)d_in[0], (const float*)d_in[1], wb, hvA, outf);

    // ping-pong: A->B->A->B->A; l=3 scatters gather sections (nt stores)
    layer_k<<<NV / 4, 128, 0, stream>>>(hvA, wb, degS, adjS, degD, adjD, dstv, outf, hvB, 0, nullptr, outf);
    layer_k<<<NV / 4, 128, 0, stream>>>(hvB, wb, degS, adjS, degD, adjD, dstv, outf, hvA, 1, nullptr, outf);
    layer_k<<<NV / 4, 128, 0, stream>>>(hvA, wb, degS, adjS, degD, adjD, dstv, outf, hvB, 2, nullptr, outf);
    layer_k<<<NV / 4, 128, 0, stream>>>(hvB, wb, degS, adjS, degD, adjD, dstv, outf, hvA, 3, outf, outf);
}